// Round 1
// baseline (625.539 us; speedup 1.0000x reference)
//
#include <hip/hip_runtime.h>
#include <math.h>

// ---------------- precompute: qvec = S@Wq + bq; A[j][h] = (Wk[j,h*32:]·q_h)/sqrt(128); c[h] ----------------
__global__ __launch_bounds__(128) void k_precompute(
    const float* __restrict__ S, const float* __restrict__ Wq, const float* __restrict__ bq,
    const float* __restrict__ Wk, const float* __restrict__ bk,
    float* __restrict__ qvec, float* __restrict__ A, float* __restrict__ cvec) {
  __shared__ float s_S[128];
  __shared__ float s_q[128];
  int j = threadIdx.x;
  s_S[j] = S[j];
  __syncthreads();
  float acc = bq[j];
  for (int i = 0; i < 128; ++i) acc += s_S[i] * Wq[i * 128 + j];
  qvec[j] = acc;
  s_q[j] = acc;
  __syncthreads();
  const float scale = 0.088388347648318447f; // 1/sqrt(128)
  for (int h = 0; h < 4; ++h) {
    float a = 0.f;
    for (int d = 0; d < 32; ++d) a += Wk[j * 128 + h * 32 + d] * s_q[h * 32 + d];
    A[j * 4 + h] = a * scale;
  }
  if (j < 4) {
    float cc = 0.f;
    for (int d = 0; d < 32; ++d) cc += bk[j * 32 + d] * s_q[j * 32 + d];
    cvec[j] = cc * scale;
  }
}

// ---------------- counting sort of point indices by zone ----------------
__global__ __launch_bounds__(256) void k_hist(const int* __restrict__ zone, int n, int* __restrict__ counts) {
  int i = blockIdx.x * blockDim.x + threadIdx.x;
  if (i < n) atomicAdd(&counts[zone[i]], 1);
}

__global__ __launch_bounds__(256) void k_scan(const int* __restrict__ counts, int R, int* __restrict__ start) {
  __shared__ int part[256];
  int t = threadIdx.x;
  int chunk = (R + 255) / 256;
  int b = t * chunk, e = min(b + chunk, R);
  int s = 0;
  for (int i = b; i < e; ++i) s += counts[i];
  part[t] = s;
  __syncthreads();
  for (int off = 1; off < 256; off <<= 1) {
    int v = (t >= off) ? part[t - off] : 0;
    __syncthreads();
    part[t] += v;
    __syncthreads();
  }
  int run = part[t] - s; // exclusive prefix
  for (int i = b; i < e; ++i) { start[i] = run; run += counts[i]; }
  if (t == 255) start[R] = part[255];
}

__global__ __launch_bounds__(256) void k_scatter(const int* __restrict__ zone, int n,
                                                 const int* __restrict__ start,
                                                 int* __restrict__ cursor, int* __restrict__ perm) {
  int i = blockIdx.x * blockDim.x + threadIdx.x;
  if (i < n) {
    int r = zone[i];
    int pos = atomicAdd(&cursor[r], 1);
    perm[start[r] + pos] = i;
  }
}

// ---------------- per-region attention accumulation (1 block = 1 region) ----------------
// Each wave processes 2 points per iteration (one per 32-lane half). Lane sl holds dims 4*sl..4*sl+3.
// Accumulates Xagg[h][dim] = sum_n p[n,h]*x[n,dim] and denom[h] = sum_n p[n,h].
__global__ __launch_bounds__(256) void k_region(
    const float* __restrict__ x, const int* __restrict__ perm, const int* __restrict__ start,
    const float* __restrict__ A, const float* __restrict__ cvec,
    float* __restrict__ Xagg, float* __restrict__ denom) {
  const int r = blockIdx.x;
  const int s0 = start[r], s1 = start[r + 1];
  const int tid = threadIdx.x;
  const int wave = tid >> 6, lane = tid & 63;
  const int half = lane >> 5, sl = lane & 31;
  const int d0 = sl * 4;

  float a[4][4];
#pragma unroll
  for (int dd = 0; dd < 4; ++dd)
#pragma unroll
    for (int h = 0; h < 4; ++h) a[dd][h] = A[(d0 + dd) * 4 + h];
  const float c0 = cvec[0], c1 = cvec[1], c2 = cvec[2], c3 = cvec[3];

  float xagg[4][4] = {};
  float dsum[4] = {};

  for (int i = s0 + wave * 2 + half; i < s1; i += 8) {
    const int idx = perm[i];
    const float4 xv = *reinterpret_cast<const float4*>(x + (size_t)idx * 128 + d0);
    float s[4];
#pragma unroll
    for (int h = 0; h < 4; ++h)
      s[h] = xv.x * a[0][h] + xv.y * a[1][h] + xv.z * a[2][h] + xv.w * a[3][h];
    // butterfly reduce within the 32-lane half
#pragma unroll
    for (int m = 1; m <= 16; m <<= 1) {
#pragma unroll
      for (int h = 0; h < 4; ++h) s[h] += __shfl_xor(s[h], m, 64);
    }
    float p[4];
    p[0] = __expf(s[0] + c0); p[1] = __expf(s[1] + c1);
    p[2] = __expf(s[2] + c2); p[3] = __expf(s[3] + c3);
#pragma unroll
    for (int h = 0; h < 4; ++h) dsum[h] += p[h];
#pragma unroll
    for (int h = 0; h < 4; ++h) {
      xagg[0][h] += p[h] * xv.x; xagg[1][h] += p[h] * xv.y;
      xagg[2][h] += p[h] * xv.z; xagg[3][h] += p[h] * xv.w;
    }
  }

  __shared__ float s_xagg[512]; // [dim][h] layout: dim*4+h
  __shared__ float s_den[4];
  for (int t = tid; t < 512; t += 256) s_xagg[t] = 0.f;
  if (tid < 4) s_den[tid] = 0.f;
  __syncthreads();
#pragma unroll
  for (int dd = 0; dd < 4; ++dd)
#pragma unroll
    for (int h = 0; h < 4; ++h) atomicAdd(&s_xagg[(d0 + dd) * 4 + h], xagg[dd][h]);
  if (sl == 0) {
#pragma unroll
    for (int h = 0; h < 4; ++h) atomicAdd(&s_den[h], dsum[h]);
  }
  __syncthreads();
  // store as Xagg[r][h][j]
  for (int t = tid; t < 512; t += 256) {
    int h = t >> 7, j = t & 127;
    Xagg[(size_t)r * 512 + t] = s_xagg[j * 4 + h];
  }
  if (tid < 4) denom[r * 4 + tid] = s_den[tid];
}

// ---------------- batched epilogue: attn -> O -> O+relu(O@Wo+bo) -> h = O2@Wg  (8 regions/block) --------
__global__ __launch_bounds__(256) void k_epilogue(
    const float* __restrict__ Xagg, const float* __restrict__ denom, const float* __restrict__ qvec,
    const float* __restrict__ Wv, const float* __restrict__ bv,
    const float* __restrict__ Wo, const float* __restrict__ bo,
    const float* __restrict__ Wg, float* __restrict__ hout, int R) {
  const int r0 = blockIdx.x * 8;
  const int tid = threadIdx.x;
  __shared__ float s_xa[8 * 512];
  __shared__ float s_den[8 * 4];
  __shared__ float s_O[8 * 128];
  __shared__ float s_O2[8 * 128];

  for (int t = tid; t < 8 * 512; t += 256) {
    int rl = t >> 9;
    s_xa[t] = (r0 + rl < R) ? Xagg[(size_t)r0 * 512 + t] : 0.f;
  }
  if (tid < 32) {
    int rl = tid >> 2;
    s_den[tid] = (r0 + rl < R) ? denom[r0 * 4 + tid] : 1.f;
  }
  __syncthreads();

  for (int o = tid; o < 1024; o += 256) {
    int rl = o >> 7, t = o & 127, h = t >> 5;
    float acc = 0.f;
    const float* xa = &s_xa[rl * 512 + h * 128];
    for (int j = 0; j < 128; ++j) acc += xa[j] * Wv[j * 128 + t];
    float dn = s_den[rl * 4 + h];
    float attn = (acc + dn * bv[t]) / fmaxf(dn, 1e-9f);
    s_O[o] = qvec[t] + attn;
  }
  __syncthreads();

  for (int o = tid; o < 1024; o += 256) {
    int rl = o >> 7, t = o & 127;
    float acc = bo[t];
    const float* ov = &s_O[rl * 128];
    for (int j = 0; j < 128; ++j) acc += ov[j] * Wo[j * 128 + t];
    s_O2[o] = s_O[o] + fmaxf(acc, 0.f);
  }
  __syncthreads();

  for (int o = tid; o < 1024; o += 256) {
    int rl = o >> 7, t = o & 127;
    float acc = 0.f;
    const float* ov = &s_O2[rl * 128];
    for (int j = 0; j < 128; ++j) acc += ov[j] * Wg[j * 128 + t];
    if (r0 + rl < R) hout[(size_t)(r0 + rl) * 128 + t] = acc;
  }
}

// ---------------- GCN ----------------
__global__ __launch_bounds__(256) void k_deg(const int* __restrict__ col, int E, int* __restrict__ deg) {
  int i = blockIdx.x * blockDim.x + threadIdx.x;
  if (i < E) atomicAdd(&deg[col[i]], 1);
}

__global__ __launch_bounds__(256) void k_dinv(const int* __restrict__ deg, int R, float* __restrict__ dinv) {
  int i = blockIdx.x * blockDim.x + threadIdx.x;
  if (i < R) dinv[i] = rsqrtf((float)(deg[i] + 1)); // +1 self loop, always > 0
}

__global__ __launch_bounds__(256) void k_selfinit(const float* __restrict__ hbuf, const float* __restrict__ dinv,
                                                  int RD, float* __restrict__ agg) {
  int i = blockIdx.x * blockDim.x + threadIdx.x;
  if (i < RD) {
    int r = i >> 7;
    float d = dinv[r];
    agg[i] = d * d * hbuf[i];
  }
}

__global__ __launch_bounds__(256) void k_edge(const int* __restrict__ row, const int* __restrict__ col, int E,
                                              const float* __restrict__ dinv, const float* __restrict__ hbuf,
                                              float* __restrict__ agg) {
  int i = blockIdx.x * blockDim.x + threadIdx.x;
  if (i < E * 128) {
    int e = i >> 7, j = i & 127;
    int r = row[e], c = col[e];
    float w = dinv[r] * dinv[c];
    atomicAdd(&agg[c * 128 + j], w * hbuf[r * 128 + j]);
  }
}

__global__ __launch_bounds__(256) void k_final(const float* __restrict__ agg, const float* __restrict__ bg,
                                               const float* __restrict__ pw, int RD, float* __restrict__ out) {
  int i = blockIdx.x * blockDim.x + threadIdx.x;
  if (i < RD) {
    int j = i & 127;
    float t = agg[i] + bg[j];
    out[i] = (t >= 0.f) ? t : pw[j] * t;
  }
}

// ---------------- host ----------------
extern "C" void kernel_launch(void* const* d_in, const int* in_sizes, int n_in,
                              void* d_out, int out_size, void* d_ws, size_t ws_size,
                              hipStream_t stream) {
  const float* x   = (const float*)d_in[0];
  const int*   zone = (const int*)d_in[1];
  const int*   eidx = (const int*)d_in[2];
  const float* S   = (const float*)d_in[4];
  const float* Wq  = (const float*)d_in[5];
  const float* bq  = (const float*)d_in[6];
  const float* Wk  = (const float*)d_in[7];
  const float* bk  = (const float*)d_in[8];
  const float* Wv  = (const float*)d_in[9];
  const float* bv  = (const float*)d_in[10];
  const float* bo  = (const float*)d_in[12];
  const float* Wo  = (const float*)d_in[11];
  const float* Wg  = (const float*)d_in[13];
  const float* bg  = (const float*)d_in[14];
  const float* pw  = (const float*)d_in[15];
  float* out = (float*)d_out;

  const int N = in_sizes[0] / 128;
  const int E = in_sizes[2] / 2;
  const int R = out_size / 128;
  const int* erow = eidx;
  const int* ecol = eidx + E;

  char* wsb = (char*)d_ws;
  size_t off = 0;
  auto alloc = [&](size_t bytes) -> void* {
    void* p = wsb + off;
    off = (off + bytes + 255) & ~(size_t)255;
    return p;
  };
  float* qvec  = (float*)alloc(128 * 4);
  float* A     = (float*)alloc(512 * 4);
  float* cvec  = (float*)alloc(4 * 4);
  int*   counts= (int*)alloc((size_t)R * 4);
  int*   startb= (int*)alloc((size_t)(R + 1) * 4);
  int*   cursor= (int*)alloc((size_t)R * 4);
  int*   deg   = (int*)alloc((size_t)R * 4);
  float* dinv  = (float*)alloc((size_t)R * 4);
  int*   perm  = (int*)alloc((size_t)N * 4);
  float* Xagg  = (float*)alloc((size_t)R * 512 * 4);
  float* denom = (float*)alloc((size_t)R * 4 * 4);
  float* hbuf  = (float*)alloc((size_t)R * 128 * 4);
  float* agg   = (float*)alloc((size_t)R * 128 * 4);

  hipMemsetAsync(counts, 0, (size_t)R * 4, stream);
  hipMemsetAsync(cursor, 0, (size_t)R * 4, stream);
  hipMemsetAsync(deg, 0, (size_t)R * 4, stream);

  k_precompute<<<1, 128, 0, stream>>>(S, Wq, bq, Wk, bk, qvec, A, cvec);
  k_hist<<<(N + 255) / 256, 256, 0, stream>>>(zone, N, counts);
  k_scan<<<1, 256, 0, stream>>>(counts, R, startb);
  k_scatter<<<(N + 255) / 256, 256, 0, stream>>>(zone, N, startb, cursor, perm);
  k_region<<<R, 256, 0, stream>>>(x, perm, startb, A, cvec, Xagg, denom);
  k_epilogue<<<(R + 7) / 8, 256, 0, stream>>>(Xagg, denom, qvec, Wv, bv, Wo, bo, Wg, hbuf, R);
  k_deg<<<(E + 255) / 256, 256, 0, stream>>>(ecol, E, deg);
  k_dinv<<<(R + 255) / 256, 256, 0, stream>>>(deg, R, dinv);
  k_selfinit<<<(R * 128 + 255) / 256, 256, 0, stream>>>(hbuf, dinv, R * 128, agg);
  k_edge<<<(E * 128 + 255) / 256, 256, 0, stream>>>(erow, ecol, E, dinv, hbuf, agg);
  k_final<<<(R * 128 + 255) / 256, 256, 0, stream>>>(agg, bg, pw, R * 128, out);
}

// Round 2
// 575.617 us; speedup vs baseline: 1.0867x; 1.0867x over previous
//
#include <hip/hip_runtime.h>
#include <math.h>

// ---------------- precompute: qvec = S@Wq + bq; A[j][h] = (Wk[j,h*32:]·q_h)/sqrt(128); c[h] ----------------
__global__ __launch_bounds__(128) void k_precompute(
    const float* __restrict__ S, const float* __restrict__ Wq, const float* __restrict__ bq,
    const float* __restrict__ Wk, const float* __restrict__ bk,
    float* __restrict__ qvec, float* __restrict__ A, float* __restrict__ cvec) {
  __shared__ float s_S[128];
  __shared__ float s_q[128];
  int j = threadIdx.x;
  s_S[j] = S[j];
  __syncthreads();
  float acc = bq[j];
  for (int i = 0; i < 128; ++i) acc += s_S[i] * Wq[i * 128 + j];
  qvec[j] = acc;
  s_q[j] = acc;
  __syncthreads();
  const float scale = 0.088388347648318447f; // 1/sqrt(128)
  for (int h = 0; h < 4; ++h) {
    float a = 0.f;
    for (int d = 0; d < 32; ++d) a += Wk[j * 128 + h * 32 + d] * s_q[h * 32 + d];
    A[j * 4 + h] = a * scale;
  }
  if (j < 4) {
    float cc = 0.f;
    for (int d = 0; d < 32; ++d) cc += bk[j * 32 + d] * s_q[j * 32 + d];
    cvec[j] = cc * scale;
  }
}

// ---------------- counting sort: histogram + scan ----------------
__global__ __launch_bounds__(256) void k_hist(const int* __restrict__ zone, int n, int* __restrict__ counts) {
  int i = blockIdx.x * blockDim.x + threadIdx.x;
  if (i < n) atomicAdd(&counts[zone[i]], 1);
}

__global__ __launch_bounds__(256) void k_scan(const int* __restrict__ counts, int R, int* __restrict__ start) {
  __shared__ int part[256];
  int t = threadIdx.x;
  int chunk = (R + 255) / 256;
  int b = t * chunk, e = min(b + chunk, R);
  int s = 0;
  for (int i = b; i < e; ++i) s += counts[i];
  part[t] = s;
  __syncthreads();
  for (int off = 1; off < 256; off <<= 1) {
    int v = (t >= off) ? part[t - off] : 0;
    __syncthreads();
    part[t] += v;
    __syncthreads();
  }
  int run = part[t] - s; // exclusive prefix
  for (int i = b; i < e; ++i) { start[i] = run; run += counts[i]; }
  if (t == 255) start[R] = part[255];
}

// head-compaction reduce: input s[4] per lane (partials over 4 dims), output = total
// score for head (lane&3), summed over the 32-lane half. 6 shuffles instead of 20.
__device__ __forceinline__ float reduce_heads(const float s0, const float s1,
                                              const float s2, const float s3, int lane) {
  float a01 = (lane & 1) ? s1 : s0;
  float b01 = (lane & 1) ? s0 : s1;
  a01 += __shfl_xor(b01, 1, 64);
  float a23 = (lane & 1) ? s3 : s2;
  float b23 = (lane & 1) ? s2 : s3;
  a23 += __shfl_xor(b23, 1, 64);
  float aa = (lane & 2) ? a23 : a01;
  float bb = (lane & 2) ? a01 : a23;
  aa += __shfl_xor(bb, 2, 64);
  aa += __shfl_xor(aa, 4, 64);
  aa += __shfl_xor(aa, 8, 64);
  aa += __shfl_xor(aa, 16, 64);
  return aa;
}

// ---------------- phase A: streaming scores -> p, scattered into region-sorted order --------
// Half-wave (32 lanes) per point, 2 points in flight per half-wave.
__global__ __launch_bounds__(256) void k_score_scatter(
    const float* __restrict__ x, const int* __restrict__ zone,
    const float* __restrict__ A, const float* __restrict__ cvec,
    const int* __restrict__ startb, int* __restrict__ cursor,
    int* __restrict__ perm, float* __restrict__ p_sorted, int N, int chunk) {
  const int tid = threadIdx.x;
  const int wave = tid >> 6, lane = tid & 63;
  const int half = lane >> 5, sl = lane & 31;
  const int d0 = sl * 4;
  float a[4][4];
#pragma unroll
  for (int dd = 0; dd < 4; ++dd)
#pragma unroll
    for (int h = 0; h < 4; ++h) a[dd][h] = A[(d0 + dd) * 4 + h];
  const float cl = cvec[lane & 3];

  const int b0 = blockIdx.x * chunk;
  const int b1 = min(N, b0 + chunk);

  for (int i = b0 + wave * 2 + half; i < b1; i += 16) {
    const int i2 = i + 8;
    const bool v2 = i2 < b1;
    const float4 xv1 = *reinterpret_cast<const float4*>(x + (size_t)i * 128 + d0);
    float4 xv2 = make_float4(0.f, 0.f, 0.f, 0.f);
    int z1 = zone[i], z2 = 0;
    if (v2) {
      xv2 = *reinterpret_cast<const float4*>(x + (size_t)i2 * 128 + d0);
      z2 = zone[i2];
    }
    float s1[4], s2[4];
#pragma unroll
    for (int h = 0; h < 4; ++h) {
      s1[h] = xv1.x * a[0][h] + xv1.y * a[1][h] + xv1.z * a[2][h] + xv1.w * a[3][h];
      s2[h] = xv2.x * a[0][h] + xv2.y * a[1][h] + xv2.z * a[2][h] + xv2.w * a[3][h];
    }
    const float r1 = reduce_heads(s1[0], s1[1], s1[2], s1[3], lane);
    const float r2 = reduce_heads(s2[0], s2[1], s2[2], s2[3], lane);
    const float p1 = __expf(r1 + cl);
    const float p2 = __expf(r2 + cl);

    int pos1 = 0;
    if (sl == 0) pos1 = startb[z1] + atomicAdd(&cursor[z1], 1);
    pos1 = __shfl(pos1, half * 32, 64);
    if (sl < 4) p_sorted[(size_t)pos1 * 4 + sl] = p1;
    if (sl == 0) perm[pos1] = i;

    if (v2) {
      int pos2 = 0;
      if (sl == 0) pos2 = startb[z2] + atomicAdd(&cursor[z2], 1);
      pos2 = __shfl(pos2, half * 32, 64);
      if (sl < 4) p_sorted[(size_t)pos2 * 4 + sl] = p2;
      if (sl == 0) perm[pos2] = i2;
    }
  }
}

// ---------------- phase B: per-region weighted gather (no shuffles, unrolled x4) ----------------
__global__ __launch_bounds__(256) void k_gather(
    const float* __restrict__ x, const int* __restrict__ perm, const int* __restrict__ startb,
    const float* __restrict__ p_sorted,
    float* __restrict__ Xagg, float* __restrict__ denom) {
  const int r = blockIdx.x;
  const int s0 = startb[r], s1 = startb[r + 1];
  const int tid = threadIdx.x;
  const int wave = tid >> 6, lane = tid & 63;
  const int half = lane >> 5, sl = lane & 31;
  const int d0 = sl * 4;

  float xagg[4][4] = {};
  float dsum[4] = {};

  for (int i = s0 + wave * 2 + half; i < s1; i += 32) {
    float4 xv[4], pp[4];
#pragma unroll
    for (int k = 0; k < 4; ++k) {
      const int j = i + k * 8;
      if (j < s1) {
        const int idx = perm[j];
        xv[k] = *reinterpret_cast<const float4*>(x + (size_t)idx * 128 + d0);
        pp[k] = *reinterpret_cast<const float4*>(p_sorted + (size_t)j * 4);
      } else {
        xv[k] = make_float4(0.f, 0.f, 0.f, 0.f);
        pp[k] = make_float4(0.f, 0.f, 0.f, 0.f);
      }
    }
#pragma unroll
    for (int k = 0; k < 4; ++k) {
      const float4 q = pp[k];
      const float4 v = xv[k];
      xagg[0][0] += q.x * v.x; xagg[0][1] += q.y * v.x; xagg[0][2] += q.z * v.x; xagg[0][3] += q.w * v.x;
      xagg[1][0] += q.x * v.y; xagg[1][1] += q.y * v.y; xagg[1][2] += q.z * v.y; xagg[1][3] += q.w * v.y;
      xagg[2][0] += q.x * v.z; xagg[2][1] += q.y * v.z; xagg[2][2] += q.z * v.z; xagg[2][3] += q.w * v.z;
      xagg[3][0] += q.x * v.w; xagg[3][1] += q.y * v.w; xagg[3][2] += q.z * v.w; xagg[3][3] += q.w * v.w;
      dsum[0] += q.x; dsum[1] += q.y; dsum[2] += q.z; dsum[3] += q.w;
    }
  }

  __shared__ float s_xagg[512]; // [dim][h] layout: dim*4+h
  __shared__ float s_den[4];
  for (int t = tid; t < 512; t += 256) s_xagg[t] = 0.f;
  if (tid < 4) s_den[tid] = 0.f;
  __syncthreads();
#pragma unroll
  for (int dd = 0; dd < 4; ++dd)
#pragma unroll
    for (int h = 0; h < 4; ++h) atomicAdd(&s_xagg[(d0 + dd) * 4 + h], xagg[dd][h]);
  if (sl == 0) {
#pragma unroll
    for (int h = 0; h < 4; ++h) atomicAdd(&s_den[h], dsum[h]);
  }
  __syncthreads();
  for (int t = tid; t < 512; t += 256) {
    int h = t >> 7, j = t & 127;
    Xagg[(size_t)r * 512 + t] = s_xagg[j * 4 + h];
  }
  if (tid < 4) denom[r * 4 + tid] = s_den[tid];
}

// ---------------- batched epilogue: attn -> O -> O+relu(O@Wo+bo) -> h = O2@Wg  (8 regions/block) --------
__global__ __launch_bounds__(256) void k_epilogue(
    const float* __restrict__ Xagg, const float* __restrict__ denom, const float* __restrict__ qvec,
    const float* __restrict__ Wv, const float* __restrict__ bv,
    const float* __restrict__ Wo, const float* __restrict__ bo,
    const float* __restrict__ Wg, float* __restrict__ hout, int R) {
  const int r0 = blockIdx.x * 8;
  const int tid = threadIdx.x;
  __shared__ float s_xa[8 * 512];
  __shared__ float s_den[8 * 4];
  __shared__ float s_O[8 * 128];
  __shared__ float s_O2[8 * 128];

  for (int t = tid; t < 8 * 512; t += 256) {
    int rl = t >> 9;
    s_xa[t] = (r0 + rl < R) ? Xagg[(size_t)r0 * 512 + t] : 0.f;
  }
  if (tid < 32) {
    int rl = tid >> 2;
    s_den[tid] = (r0 + rl < R) ? denom[r0 * 4 + tid] : 1.f;
  }
  __syncthreads();

  for (int o = tid; o < 1024; o += 256) {
    int rl = o >> 7, t = o & 127, h = t >> 5;
    float acc = 0.f;
    const float* xa = &s_xa[rl * 512 + h * 128];
    for (int j = 0; j < 128; ++j) acc += xa[j] * Wv[j * 128 + t];
    float dn = s_den[rl * 4 + h];
    float attn = (acc + dn * bv[t]) / fmaxf(dn, 1e-9f);
    s_O[o] = qvec[t] + attn;
  }
  __syncthreads();

  for (int o = tid; o < 1024; o += 256) {
    int rl = o >> 7, t = o & 127;
    float acc = bo[t];
    const float* ov = &s_O[rl * 128];
    for (int j = 0; j < 128; ++j) acc += ov[j] * Wo[j * 128 + t];
    s_O2[o] = s_O[o] + fmaxf(acc, 0.f);
  }
  __syncthreads();

  for (int o = tid; o < 1024; o += 256) {
    int rl = o >> 7, t = o & 127;
    float acc = 0.f;
    const float* ov = &s_O2[rl * 128];
    for (int j = 0; j < 128; ++j) acc += ov[j] * Wg[j * 128 + t];
    if (r0 + rl < R) hout[(size_t)(r0 + rl) * 128 + t] = acc;
  }
}

// ---------------- GCN ----------------
__global__ __launch_bounds__(256) void k_deg(const int* __restrict__ col, int E, int* __restrict__ deg) {
  int i = blockIdx.x * blockDim.x + threadIdx.x;
  if (i < E) atomicAdd(&deg[col[i]], 1);
}

__global__ __launch_bounds__(256) void k_dinv(const int* __restrict__ deg, int R, float* __restrict__ dinv) {
  int i = blockIdx.x * blockDim.x + threadIdx.x;
  if (i < R) dinv[i] = rsqrtf((float)(deg[i] + 1)); // +1 self loop, always > 0
}

__global__ __launch_bounds__(256) void k_selfinit(const float* __restrict__ hbuf, const float* __restrict__ dinv,
                                                  int RD, float* __restrict__ agg) {
  int i = blockIdx.x * blockDim.x + threadIdx.x;
  if (i < RD) {
    int r = i >> 7;
    float d = dinv[r];
    agg[i] = d * d * hbuf[i];
  }
}

__global__ __launch_bounds__(256) void k_edge(const int* __restrict__ row, const int* __restrict__ col, int E,
                                              const float* __restrict__ dinv, const float* __restrict__ hbuf,
                                              float* __restrict__ agg) {
  int i = blockIdx.x * blockDim.x + threadIdx.x;
  if (i < E * 128) {
    int e = i >> 7, j = i & 127;
    int r = row[e], c = col[e];
    float w = dinv[r] * dinv[c];
    atomicAdd(&agg[c * 128 + j], w * hbuf[r * 128 + j]);
  }
}

__global__ __launch_bounds__(256) void k_final(const float* __restrict__ agg, const float* __restrict__ bg,
                                               const float* __restrict__ pw, int RD, float* __restrict__ out) {
  int i = blockIdx.x * blockDim.x + threadIdx.x;
  if (i < RD) {
    int j = i & 127;
    float t = agg[i] + bg[j];
    out[i] = (t >= 0.f) ? t : pw[j] * t;
  }
}

// ---------------- host ----------------
extern "C" void kernel_launch(void* const* d_in, const int* in_sizes, int n_in,
                              void* d_out, int out_size, void* d_ws, size_t ws_size,
                              hipStream_t stream) {
  const float* x   = (const float*)d_in[0];
  const int*   zone = (const int*)d_in[1];
  const int*   eidx = (const int*)d_in[2];
  const float* S   = (const float*)d_in[4];
  const float* Wq  = (const float*)d_in[5];
  const float* bq  = (const float*)d_in[6];
  const float* Wk  = (const float*)d_in[7];
  const float* bk  = (const float*)d_in[8];
  const float* Wv  = (const float*)d_in[9];
  const float* bv  = (const float*)d_in[10];
  const float* Wo  = (const float*)d_in[11];
  const float* bo  = (const float*)d_in[12];
  const float* Wg  = (const float*)d_in[13];
  const float* bg  = (const float*)d_in[14];
  const float* pw  = (const float*)d_in[15];
  float* out = (float*)d_out;

  const int N = in_sizes[0] / 128;
  const int E = in_sizes[2] / 2;
  const int R = out_size / 128;
  const int* erow = eidx;
  const int* ecol = eidx + E;

  char* wsb = (char*)d_ws;
  size_t off = 0;
  auto alloc = [&](size_t bytes) -> void* {
    void* p = wsb + off;
    off = (off + bytes + 255) & ~(size_t)255;
    return p;
  };
  float* qvec  = (float*)alloc(128 * 4);
  float* A     = (float*)alloc(512 * 4);
  float* cvec  = (float*)alloc(4 * 4);
  int*   counts= (int*)alloc((size_t)R * 4);
  int*   startb= (int*)alloc((size_t)(R + 1) * 4);
  int*   cursor= (int*)alloc((size_t)R * 4);
  int*   deg   = (int*)alloc((size_t)R * 4);
  float* dinv  = (float*)alloc((size_t)R * 4);
  int*   perm  = (int*)alloc((size_t)N * 4);
  float* p_sorted = (float*)alloc((size_t)N * 4 * 4);
  float* Xagg  = (float*)alloc((size_t)R * 512 * 4);
  float* denom = (float*)alloc((size_t)R * 4 * 4);
  float* hbuf  = (float*)alloc((size_t)R * 128 * 4);
  float* agg   = (float*)alloc((size_t)R * 128 * 4);

  hipMemsetAsync(counts, 0, (size_t)R * 4, stream);
  hipMemsetAsync(cursor, 0, (size_t)R * 4, stream);
  hipMemsetAsync(deg, 0, (size_t)R * 4, stream);

  k_precompute<<<1, 128, 0, stream>>>(S, Wq, bq, Wk, bk, qvec, A, cvec);
  k_hist<<<(N + 255) / 256, 256, 0, stream>>>(zone, N, counts);
  k_scan<<<1, 256, 0, stream>>>(counts, R, startb);
  const int NB = 2048;
  const int chunk = (((N + NB - 1) / NB) + 15) & ~15;
  k_score_scatter<<<NB, 256, 0, stream>>>(x, zone, A, cvec, startb, cursor, perm, p_sorted, N, chunk);
  k_gather<<<R, 256, 0, stream>>>(x, perm, startb, p_sorted, Xagg, denom);
  k_epilogue<<<(R + 7) / 8, 256, 0, stream>>>(Xagg, denom, qvec, Wv, bv, Wo, bo, Wg, hbuf, R);
  k_deg<<<(E + 255) / 256, 256, 0, stream>>>(ecol, E, deg);
  k_dinv<<<(R + 255) / 256, 256, 0, stream>>>(deg, R, dinv);
  k_selfinit<<<(R * 128 + 255) / 256, 256, 0, stream>>>(hbuf, dinv, R * 128, agg);
  k_edge<<<(E * 128 + 255) / 256, 256, 0, stream>>>(erow, ecol, E, dinv, hbuf, agg);
  k_final<<<(R * 128 + 255) / 256, 256, 0, stream>>>(agg, bg, pw, R * 128, out);
}